// Round 9
// baseline (277.873 us; speedup 1.0000x reference)
//
#include <hip/hip_runtime.h>
#include <math.h>

// ---------------------------------------------------------------------------
// SGCN forward — CSR pull aggregation + MFMA dense layers.
//
// R13 = R12 resubmitted (R12's bench died on container acquire — infra flake,
// no kernel signal; source audited for container-killers, none found).
//
// R12: R11's mega_k bucket phase was register-SPILLED (val[32]+pr[32] = 64
// regs vs VGPR_Count 36 -> scratch) and under-subscribed (306 blocks = 1.2/CU,
// occ 20%, 48.5us at 4% VALU). Rebuilt with NO per-edge register state:
//   * bucket: two-pass grid-stride. Pass1 count LDS hist -> one global
//     reserve per bucket per block -> pass2 re-reads own L2-resident range
//     (19KB) and places via LDS rank atomic. 1024 blocks (4/CU, 16 waves).
//   * cvt grid-stride at 512 blocks (was 6250 one-shot blocks).
//   * scatter_k at 512 threads (scans guarded to 256 lanes): 2x resident
//     waves for its latency-bound LDS-atomic phases.
// agg_k NOT touched: R11's 16-stream probe moved 46.3->44.9 (~0) => it sits
// at the random-gather fabric ceiling (~3.46 TB/s eff). gemm_k unchanged.
// ---------------------------------------------------------------------------

typedef _Float16 h4 __attribute__((ext_vector_type(4)));
typedef _Float16 h8 __attribute__((ext_vector_type(8)));
typedef float f32x4 __attribute__((ext_vector_type(4)));

__device__ inline h8 shflx8(h8 v, int m) {
    int4 i = __builtin_bit_cast(int4, v);
    i.x = __shfl_xor(i.x, m);
    i.y = __shfl_xor(i.y, m);
    i.z = __shfl_xor(i.z, m);
    i.w = __shfl_xor(i.w, m);
    return __builtin_bit_cast(h8, i);
}

__device__ inline float fast_tanh(float v) {
    float e = __expf(2.0f * v);
    return 1.0f - 2.0f / (e + 1.0f);
}

// ------------------------------- CSR build ---------------------------------
// Bucket = 512 consecutive flattened dst ids (2n space: pos then neg).
// Record = (nd & 511) << 17 | src   (src < 2^17, rel < 2^9 -> 26 bits).

#define BSHIFT 9
#define BSIZE  512
#define NBMAX  512
#define CAP    8192   // per-bucket record capacity; mean 6400, +22 sigma

// ---- weight fragment maps (B 192x64 packed in MFMA fragment order) --------
// frag (kk,nt), lane l, elem j holds B[kk*32 + (l>>4)*8 + j][nt*16 + (l&15)].
// A1 row = [aggP(x) 0..63 | aggN(x) 64..127 | x 128..191]
// A2 row = [Mp(zp) 0..31 | Mp(zn) 32..63 | Mn(zp) 64..95 | Mn(zn) 96..127 |
//           zp 128..159 | zn 160..191]

__device__ inline float b1map(const float* W1p, const float* W1n, int k, int c)
{
    if (c < 32) {
        if (k < 64)   return W1p[k * 32 + c];            // aggP -> W1p rows 0..63
        if (k >= 128) return W1p[(k - 64) * 32 + c];     // x    -> W1p rows 64..127
        return 0.0f;
    } else {
        int cn = c - 32;
        if (k >= 64)  return W1n[(k - 64) * 32 + cn];    // aggN rows 0..63, x rows 64..127
        return 0.0f;
    }
}

__device__ inline float b2map(const float* W2p, const float* W2n, int k, int c)
{
    if (c < 32) {
        if (k < 32)               return W2p[k * 32 + c];              // Mp(zp)
        if (k >= 96 && k < 128)   return W2p[(k - 96 + 32) * 32 + c];  // Mn(zn)
        if (k >= 128 && k < 160)  return W2p[(k - 128 + 64) * 32 + c]; // zp
        return 0.0f;
    } else {
        int cn = c - 32;
        if (k >= 32 && k < 64)    return W2n[(k - 32) * 32 + cn];       // Mp(zn)
        if (k >= 64 && k < 96)    return W2n[(k - 64 + 32) * 32 + cn];  // Mn(zp)
        if (k >= 160)             return W2n[(k - 160 + 64) * 32 + cn]; // zn
        return 0.0f;
    }
}

// ---- merged: bucket (blocks [0,bblocks)) | cvt (grid-stride) | prep -------

__global__ void __launch_bounds__(256) mega_k(
    const int* __restrict__ pos, const int* __restrict__ neg,
    int* __restrict__ pcnt, unsigned* __restrict__ ebuf,
    int E, int n, int nb, int bblocks,
    const float4* __restrict__ x, h4* __restrict__ xh, int n4, int cvtBlocks,
    const float* __restrict__ W1p, const float* __restrict__ W1n,
    const float* __restrict__ W2p, const float* __restrict__ W2n,
    _Float16* __restrict__ Bpack)
{
    int tid = threadIdx.x;
    int bid = blockIdx.x;

    if (bid >= bblocks) {
        int cb = bid - bblocks;
        if (cb < cvtBlocks) {                       // ---- x -> fp16 (stride) ----
            int gs = cvtBlocks * 256;
            for (int i = cb * 256 + tid; i < n4; i += gs) {
                float4 v = x[i];
                h4 o = { (_Float16)v.x, (_Float16)v.y, (_Float16)v.z, (_Float16)v.w };
                xh[i] = o;
            }
        } else {                                    // ---- weight prep ----
            int slot = (cb - cvtBlocks) * 256 + tid;   // 0..3071
            if (slot < 2 * 24 * 64) {
                int mat  = slot / (24 * 64);
                int rem  = slot % (24 * 64);
                int fg   = rem / 64;          // kk*4 + nt
                int lane = rem % 64;
                int kk = fg >> 2, nt = fg & 3;
                int g = lane >> 4, m = lane & 15;
                _Float16* dst = Bpack + (size_t)slot * 8;
                int c = nt * 16 + m;
                #pragma unroll
                for (int j = 0; j < 8; ++j) {
                    int k = kk * 32 + g * 8 + j;
                    float v = mat ? b2map(W2p, W2n, k, c) : b1map(W1p, W1n, k, c);
                    dst[j] = (_Float16)v;
                }
            }
        }
        return;
    }

    // ---- bucket: two-pass over this block's contiguous edge range ----
    __shared__ int cnt[NBMAX], gbase[NBMAX];
    int per = (2 * E + bblocks - 1) / bblocks;
    int e0 = bid * per;
    int e1 = min(e0 + per, 2 * E);

    for (int i = tid; i < nb; i += 256) cnt[i] = 0;
    __syncthreads();

    // pass 1: count (dst only)
    for (int e = e0 + tid; e < e1; e += 256) {
        int nd = (e < E) ? pos[E + e] : n + neg[E + (e - E)];
        atomicAdd(&cnt[nd >> BSHIFT], 1);
    }
    __syncthreads();
    // reserve global space, reset cnt for rank use
    for (int i = tid; i < nb; i += 256) {
        int c = cnt[i];
        gbase[i] = c ? atomicAdd(&pcnt[i], c) : 0;
        cnt[i] = 0;
    }
    __syncthreads();
    // pass 2: place (range is L2-resident from pass 1)
    for (int e = e0 + tid; e < e1; e += 256) {
        int nd, sr;
        if (e < E) { nd = pos[E + e];                 sr = pos[e]; }
        else       { int ee = e - E; nd = n + neg[E + ee]; sr = neg[ee]; }
        int p = nd >> BSHIFT;
        int r = gbase[p] + atomicAdd(&cnt[p], 1);
        if (r < CAP)
            ebuf[(size_t)p * CAP + r] =
                ((unsigned)(nd & (BSIZE - 1)) << 17) | (unsigned)sr;
    }
}

// One block per bucket, 512 threads (scan sections use 256 lanes). Inline
// scan of bucket counts, LDS histogram -> scan -> dense cur write -> LDS
// staging of col segment -> contiguous global stream-out.
__global__ void __launch_bounds__(512) scatter_k(
    const unsigned* __restrict__ ebuf, const int* __restrict__ pcnt,
    int* __restrict__ cur, int* __restrict__ col, int n, int nb)
{
    __shared__ int lcnt[BSIZE], lbase[BSIZE], sc[256], bb[NBMAX];
    __shared__ int lcol[CAP];
    int p = blockIdx.x;
    int tid = threadIdx.x;
    int n2 = 2 * n;
    int lo = p << BSHIFT;
    int nn = min(BSIZE, n2 - lo);
    int cnt = min(pcnt[p], CAP);
    const unsigned* buf = ebuf + (size_t)p * CAP;

    // inline exclusive scan of pcnt[0..nb) — 256 scan lanes, 2 elems each
    {
        int a0 = 0, a1 = 0, s = 0;
        if (tid < 256) {
            a0 = (2 * tid     < nb) ? pcnt[2 * tid]     : 0;
            a1 = (2 * tid + 1 < nb) ? pcnt[2 * tid + 1] : 0;
            s = a0 + a1;
            sc[tid] = s;
        }
        __syncthreads();
        for (int off = 1; off < 256; off <<= 1) {
            int t = (tid < 256 && tid >= off) ? sc[tid - off] : 0;
            __syncthreads();
            if (tid < 256) sc[tid] += t;
            __syncthreads();
        }
        if (tid < 256) {
            int excl = sc[tid] - s;
            bb[2 * tid]     = excl;
            bb[2 * tid + 1] = excl + a0;
        }
    }

    for (int i = tid; i < BSIZE; i += 512) lcnt[i] = 0;
    __syncthreads();
    for (int i = tid; i < cnt; i += 512)
        atomicAdd(&lcnt[buf[i] >> 17], 1);
    __syncthreads();
    // scan lcnt[512] -> lbase (exclusive)
    {
        int a0 = 0, a1 = 0, s = 0;
        if (tid < 256) {
            a0 = lcnt[2 * tid]; a1 = lcnt[2 * tid + 1];
            s = a0 + a1;
            sc[tid] = s;
        }
        __syncthreads();
        for (int off = 1; off < 256; off <<= 1) {
            int t = (tid < 256 && tid >= off) ? sc[tid - off] : 0;
            __syncthreads();
            if (tid < 256) sc[tid] += t;
            __syncthreads();
        }
        if (tid < 256) {
            int excl = sc[tid] - s;
            lbase[2 * tid]     = excl;
            lbase[2 * tid + 1] = excl + a0;
        }
    }
    __syncthreads();
    int gb = bb[p];
    for (int i = tid; i < nn; i += 512)            // inclusive prefix -> cur
        cur[lo + i] = gb + lbase[i] + lcnt[i];
    __syncthreads();
    for (int i = tid; i < cnt; i += 512) {         // place into LDS staging
        unsigned v = buf[i];
        int slot = atomicAdd(&lbase[v >> 17], 1);
        lcol[slot] = (int)(v & 0x1FFFFu);
    }
    __syncthreads();
    for (int t = tid; t < cnt; t += 512)           // dense stream-out
        col[gb + t] = lcol[t];
}

// ------------------------------- aggregation -------------------------------
// One wave per node, 16 streams: stream s = lane>>2 (0-7 pos stride-8,
// 8-15 neg), lane f = lane&3; each lane accumulates h8 chunks f and f+4.
// Reduce across strides with shfl_xor 4/8/16 (list bit 32 untouched).
// At the random-gather fabric ceiling (R11 probe) — do not touch.

__global__ void __launch_bounds__(256) agg_k(
    const h8* __restrict__ feat8,
    const int* __restrict__ cur, const int* __restrict__ col,
    h8* __restrict__ ag8, int n)
{
    int tid = threadIdx.x;
    int wave = tid >> 6, lane = tid & 63;
    int s = lane >> 2, f = lane & 3;
    int list = s >> 3;            // 0 = pos, 1 = neg
    int sub = s & 7;              // stride-8 phase

    int stride = gridDim.x * 4;
    for (int node = blockIdx.x * 4 + wave; node < n; node += stride) {
        int idx = list ? n + node : node;
        int r0 = idx ? cur[idx - 1] : 0;
        int r1 = cur[idx];

        h8 acc0 = {}, acc1 = {};
        #pragma unroll 2
        for (int it = r0 + sub; it < r1; it += 8) {
            unsigned srcb = (unsigned)col[it] * 8;
            acc0 = acc0 + feat8[srcb + f];
            acc1 = acc1 + feat8[srcb + 4 + f];
        }
        acc0 = acc0 + shflx8(acc0, 4);
        acc1 = acc1 + shflx8(acc1, 4);
        acc0 = acc0 + shflx8(acc0, 8);
        acc1 = acc1 + shflx8(acc1, 8);
        acc0 = acc0 + shflx8(acc0, 16);
        acc1 = acc1 + shflx8(acc1, 16);
        _Float16 inv = (_Float16)(1.0f / (float)max(r1 - r0, 1));
        h8 iv = { inv, inv, inv, inv, inv, inv, inv, inv };
        if (sub == 0) {
            ag8[(unsigned)(node * 16 + list * 8 + f)]     = acc0 * iv;
            ag8[(unsigned)(node * 16 + list * 8 + 4 + f)] = acc1 * iv;
        }
    }
}

// --------------------------------- GEMM ------------------------------------
// [64 nodes x 192] @ [192 x 64] per block (4 waves x 16-node tiles).
// A staged in LDS (row stride 200 fp16). D layout (verified):
// col = lane&15, row = (lane>>4)*4 + reg.

#define ROWP 200

__global__ void __launch_bounds__(256) gemm_k(
    const h8* __restrict__ ag8, const h8* __restrict__ feat8,
    const h8* __restrict__ Bp,
    const float* __restrict__ bp, const float* __restrict__ bn,
    float* __restrict__ outf, _Float16* __restrict__ outh,
    int f32out, int n)
{
    __shared__ _Float16 A_lds[64 * ROWP];   // 25.6 KB
    int tid = threadIdx.x;
    int base = blockIdx.x * 64;

    // stage A: per row, 16 h8 chunks of ag (128 h) + 8 h8 chunks of feat (64 h)
    for (int ch = tid; ch < 64 * 24; ch += 256) {
        int r = ch / 24, p = ch % 24;
        int row = min(base + r, n - 1);
        h8 v = (p < 16) ? ag8[(size_t)row * 16 + p]
                        : feat8[(size_t)row * 8 + (p - 16)];
        *(h8*)&A_lds[r * ROWP + p * 8] = v;
    }
    __syncthreads();

    int w = tid >> 6, lane = tid & 63;
    int m = lane & 15, g = lane >> 4;

    h8 a[6];
    #pragma unroll
    for (int kk = 0; kk < 6; ++kk)
        a[kk] = *(const h8*)&A_lds[(w * 16 + m) * ROWP + kk * 32 + g * 8];

    #pragma unroll
    for (int nt = 0; nt < 4; ++nt) {
        f32x4 acc = { 0.f, 0.f, 0.f, 0.f };
        #pragma unroll
        for (int kk = 0; kk < 6; ++kk) {
            h8 b = Bp[(kk * 4 + nt) * 64 + lane];
            acc = __builtin_amdgcn_mfma_f32_16x16x32_f16(a[kk], b, acc, 0, 0, 0);
        }
        int colc = nt * 16 + m;
        float bias = (colc < 32) ? bp[colc] : bn[colc - 32];
        #pragma unroll
        for (int reg = 0; reg < 4; ++reg) {
            int node = base + w * 16 + g * 4 + reg;
            if (node < n) {
                float val = fast_tanh(acc[reg] + bias);
                if (f32out) outf[(size_t)node * 64 + colc] = val;
                else        outh[(size_t)node * 64 + colc] = (_Float16)val;
            }
        }
    }
}

extern "C" void kernel_launch(void* const* d_in, const int* in_sizes, int n_in,
                              void* d_out, int out_size, void* d_ws, size_t ws_size,
                              hipStream_t stream)
{
    const float* x   = (const float*)d_in[0];
    const float* W1p = (const float*)d_in[1];
    const float* b1p = (const float*)d_in[2];
    const float* W1n = (const float*)d_in[3];
    const float* b1n = (const float*)d_in[4];
    const float* W2p = (const float*)d_in[5];
    const float* b2p = (const float*)d_in[6];
    const float* W2n = (const float*)d_in[7];
    const float* b2n = (const float*)d_in[8];
    const int*   pos = (const int*)d_in[9];
    const int*   neg = (const int*)d_in[10];

    int n = in_sizes[0] / 64;       // 100000
    int E = in_sizes[9] / 2;        // 1250000
    int n2 = 2 * n;
    int nb = (n2 + BSIZE - 1) / BSIZE;   // 391 buckets

    // ws: pcnt[512] | cur[2n] | col[2E] | Bpack[2*24*64*8 h] | xh[n*64 h] |
    //     U = max(ebuf nb*CAP u32, zh n*64 h)
    // ag (n x 128 h = 25.6MB) lives in d_out (each gemm block reads exactly
    // the ag rows it later overwrites).
    int*      pcnt  = (int*)d_ws;
    int*      cur   = pcnt + NBMAX;
    int*      col   = cur + n2;
    _Float16* Bpack = (_Float16*)(col + 2 * (size_t)E);
    _Float16* xh    = Bpack + 2 * 24 * 64 * 8;
    unsigned* ebuf  = (unsigned*)(xh + (size_t)n * 64);
    _Float16* zh    = (_Float16*)ebuf;            // aliases ebuf (dead after scatter)
    h8*       ag8   = (h8*)d_out;

    hipMemsetAsync(pcnt, 0, NBMAX * sizeof(int), stream);

    int bblocks = 1024;             // 4 blocks/CU, 16 waves/CU for the bucket phase
    int n4 = n * 16;
    int cvtBlocks = 512;            // grid-stride cvt

    mega_k<<<bblocks + cvtBlocks + 12, 256, 0, stream>>>(
        pos, neg, pcnt, ebuf, E, n, nb, bblocks,
        (const float4*)x, (h4*)xh, n4, cvtBlocks,
        W1p, W1n, W2p, W2n, Bpack);

    scatter_k<<<nb, 512, 0, stream>>>(ebuf, pcnt, cur, col, n, nb);

    int ablocks = 2048;
    int gblocks = (n + 63) / 64;

    // layer 1: agg(x) -> ag ; gemm(A1=[ag|x]) -> zh (fp16)
    agg_k <<<ablocks, 256, 0, stream>>>((const h8*)xh, cur, col, ag8, n);
    gemm_k<<<gblocks, 256, 0, stream>>>(ag8, (const h8*)xh, (const h8*)Bpack,
                                        b1p, b1n, nullptr, zh, 0, n);

    // layer 2: agg(z) -> ag ; gemm(A2=[Mp|Mn|z]) -> out (fp32)
    agg_k <<<ablocks, 256, 0, stream>>>((const h8*)zh, cur, col, ag8, n);
    gemm_k<<<gblocks, 256, 0, stream>>>(ag8, (const h8*)zh,
                                        (const h8*)(Bpack + 24 * 64 * 8),
                                        b2p, b2n, (float*)d_out, nullptr, 1, n);
}

// Round 10
// 264.915 us; speedup vs baseline: 1.0489x; 1.0489x over previous
//
#include <hip/hip_runtime.h>
#include <math.h>

// ---------------------------------------------------------------------------
// SGCN forward — CSR pull aggregation + MFMA dense layers.
//
// R14: R13 falsified the spill/occupancy theory for the bucket phase (clean
// 8-VGPR two-pass @ 4 blocks/CU still 52us, nothing saturated). Remaining
// candidate with arithmetic that reaches 125K cycles: 400K same-address
// returning atomicAdds on 391 pcnt words (~25 lines) at the coherence point,
// each block WAITING on its reserve before placing. Fix:
//   * pcnt replicated x8 (replica = bid&7, separate cache lines); ebuf bucket
//     regions pre-partitioned into 8 replica sub-chunks (RCAP=1024 = mean
//     400 + 22sigma) -> per-address queue depth /8, no rank coordination.
//   * 2048 bucket blocks (8/CU, full wave occupancy) for latency hiding.
//   * scatter_k streams 8 sub-chunks per bucket; totals = sum_r min(.,RCAP).
// agg_k frozen at measured random-gather fabric ceiling (R11 probe).
// gemm_k / cvt / prep unchanged.
// ---------------------------------------------------------------------------

typedef _Float16 h4 __attribute__((ext_vector_type(4)));
typedef _Float16 h8 __attribute__((ext_vector_type(8)));
typedef float f32x4 __attribute__((ext_vector_type(4)));

__device__ inline h8 shflx8(h8 v, int m) {
    int4 i = __builtin_bit_cast(int4, v);
    i.x = __shfl_xor(i.x, m);
    i.y = __shfl_xor(i.y, m);
    i.z = __shfl_xor(i.z, m);
    i.w = __shfl_xor(i.w, m);
    return __builtin_bit_cast(h8, i);
}

__device__ inline float fast_tanh(float v) {
    float e = __expf(2.0f * v);
    return 1.0f - 2.0f / (e + 1.0f);
}

// ------------------------------- CSR build ---------------------------------
// Bucket = 512 consecutive flattened dst ids (2n space: pos then neg).
// Record = (nd & 511) << 17 | src   (src < 2^17, rel < 2^9 -> 26 bits).
// ebuf bucket region: 8 replica sub-chunks of RCAP records each.

#define BSHIFT 9
#define BSIZE  512
#define NBMAX  512
#define NREP   8
#define RCAP   1024   // per-(replica,bucket) capacity; mean 400, +22 sigma
#define CAP    (NREP * RCAP)

// ---- weight fragment maps (B 192x64 packed in MFMA fragment order) --------
// frag (kk,nt), lane l, elem j holds B[kk*32 + (l>>4)*8 + j][nt*16 + (l&15)].
// A1 row = [aggP(x) 0..63 | aggN(x) 64..127 | x 128..191]
// A2 row = [Mp(zp) 0..31 | Mp(zn) 32..63 | Mn(zp) 64..95 | Mn(zn) 96..127 |
//           zp 128..159 | zn 160..191]

__device__ inline float b1map(const float* W1p, const float* W1n, int k, int c)
{
    if (c < 32) {
        if (k < 64)   return W1p[k * 32 + c];            // aggP -> W1p rows 0..63
        if (k >= 128) return W1p[(k - 64) * 32 + c];     // x    -> W1p rows 64..127
        return 0.0f;
    } else {
        int cn = c - 32;
        if (k >= 64)  return W1n[(k - 64) * 32 + cn];    // aggN rows 0..63, x rows 64..127
        return 0.0f;
    }
}

__device__ inline float b2map(const float* W2p, const float* W2n, int k, int c)
{
    if (c < 32) {
        if (k < 32)               return W2p[k * 32 + c];              // Mp(zp)
        if (k >= 96 && k < 128)   return W2p[(k - 96 + 32) * 32 + c];  // Mn(zn)
        if (k >= 128 && k < 160)  return W2p[(k - 128 + 64) * 32 + c]; // zp
        return 0.0f;
    } else {
        int cn = c - 32;
        if (k >= 32 && k < 64)    return W2n[(k - 32) * 32 + cn];       // Mp(zn)
        if (k >= 64 && k < 96)    return W2n[(k - 64 + 32) * 32 + cn];  // Mn(zp)
        if (k >= 160)             return W2n[(k - 160 + 64) * 32 + cn]; // zn
        return 0.0f;
    }
}

// ---- merged: bucket (blocks [0,bblocks)) | cvt (grid-stride) | prep -------

__global__ void __launch_bounds__(256) mega_k(
    const int* __restrict__ pos, const int* __restrict__ neg,
    int* __restrict__ pcntR, unsigned* __restrict__ ebuf,
    int E, int n, int nb, int bblocks,
    const float4* __restrict__ x, h4* __restrict__ xh, int n4, int cvtBlocks,
    const float* __restrict__ W1p, const float* __restrict__ W1n,
    const float* __restrict__ W2p, const float* __restrict__ W2n,
    _Float16* __restrict__ Bpack)
{
    int tid = threadIdx.x;
    int bid = blockIdx.x;

    if (bid >= bblocks) {
        int cb = bid - bblocks;
        if (cb < cvtBlocks) {                       // ---- x -> fp16 (stride) ----
            int gs = cvtBlocks * 256;
            for (int i = cb * 256 + tid; i < n4; i += gs) {
                float4 v = x[i];
                h4 o = { (_Float16)v.x, (_Float16)v.y, (_Float16)v.z, (_Float16)v.w };
                xh[i] = o;
            }
        } else {                                    // ---- weight prep ----
            int slot = (cb - cvtBlocks) * 256 + tid;   // 0..3071
            if (slot < 2 * 24 * 64) {
                int mat  = slot / (24 * 64);
                int rem  = slot % (24 * 64);
                int fg   = rem / 64;          // kk*4 + nt
                int lane = rem % 64;
                int kk = fg >> 2, nt = fg & 3;
                int g = lane >> 4, m = lane & 15;
                _Float16* dst = Bpack + (size_t)slot * 8;
                int c = nt * 16 + m;
                #pragma unroll
                for (int j = 0; j < 8; ++j) {
                    int k = kk * 32 + g * 8 + j;
                    float v = mat ? b2map(W2p, W2n, k, c) : b1map(W1p, W1n, k, c);
                    dst[j] = (_Float16)v;
                }
            }
        }
        return;
    }

    // ---- bucket: two-pass over this block's contiguous edge range ----
    __shared__ int cnt[NBMAX], gbase[NBMAX];
    int rep = bid & (NREP - 1);
    int per = (2 * E + bblocks - 1) / bblocks;
    int e0 = bid * per;
    int e1 = min(e0 + per, 2 * E);

    for (int i = tid; i < nb; i += 256) cnt[i] = 0;
    __syncthreads();

    // pass 1: count (dst only)
    for (int e = e0 + tid; e < e1; e += 256) {
        int nd = (e < E) ? pos[E + e] : n + neg[E + (e - E)];
        atomicAdd(&cnt[nd >> BSHIFT], 1);
    }
    __syncthreads();
    // reserve within own replica, reset cnt for rank use
    for (int i = tid; i < nb; i += 256) {
        int c = cnt[i];
        gbase[i] = c ? atomicAdd(&pcntR[rep * NBMAX + i], c) : 0;
        cnt[i] = 0;
    }
    __syncthreads();
    // pass 2: place (range is L2-resident from pass 1)
    for (int e = e0 + tid; e < e1; e += 256) {
        int nd, sr;
        if (e < E) { nd = pos[E + e];                 sr = pos[e]; }
        else       { int ee = e - E; nd = n + neg[E + ee]; sr = neg[ee]; }
        int p = nd >> BSHIFT;
        int r = gbase[p] + atomicAdd(&cnt[p], 1);
        if (r < RCAP)
            ebuf[(size_t)p * CAP + rep * RCAP + r] =
                ((unsigned)(nd & (BSIZE - 1)) << 17) | (unsigned)sr;
    }
}

// One block per bucket, 512 threads (scan sections use 256 lanes). Inline
// scan of per-bucket totals (sum over 8 replicas), LDS histogram over the 8
// sub-chunks -> scan -> dense cur write -> LDS staging -> contiguous out.
__global__ void __launch_bounds__(512) scatter_k(
    const unsigned* __restrict__ ebuf, const int* __restrict__ pcntR,
    int* __restrict__ cur, int* __restrict__ col, int n, int nb)
{
    __shared__ int lcnt[BSIZE], lbase[BSIZE], sc[256], bb[NBMAX], crp[NREP];
    __shared__ int lcol[CAP];
    int p = blockIdx.x;
    int tid = threadIdx.x;
    int n2 = 2 * n;
    int lo = p << BSHIFT;
    int nn = min(BSIZE, n2 - lo);
    const unsigned* bbuf = ebuf + (size_t)p * CAP;

    if (tid < NREP) crp[tid] = min(pcntR[tid * NBMAX + p], RCAP);

    // inline exclusive scan of per-bucket totals — 256 scan lanes, 2 each
    {
        int a0 = 0, a1 = 0, s = 0;
        if (tid < 256) {
            #pragma unroll
            for (int r = 0; r < NREP; ++r) {
                if (2 * tid     < nb) a0 += min(pcntR[r * NBMAX + 2 * tid],     RCAP);
                if (2 * tid + 1 < nb) a1 += min(pcntR[r * NBMAX + 2 * tid + 1], RCAP);
            }
            s = a0 + a1;
            sc[tid] = s;
        }
        __syncthreads();
        for (int off = 1; off < 256; off <<= 1) {
            int t = (tid < 256 && tid >= off) ? sc[tid - off] : 0;
            __syncthreads();
            if (tid < 256) sc[tid] += t;
            __syncthreads();
        }
        if (tid < 256) {
            int excl = sc[tid] - s;
            bb[2 * tid]     = excl;
            bb[2 * tid + 1] = excl + a0;
        }
    }

    for (int i = tid; i < BSIZE; i += 512) lcnt[i] = 0;
    __syncthreads();
    int cnttot = crp[0] + crp[1] + crp[2] + crp[3] +
                 crp[4] + crp[5] + crp[6] + crp[7];
    #pragma unroll
    for (int r = 0; r < NREP; ++r) {
        int c = crp[r];
        const unsigned* buf = bbuf + r * RCAP;
        for (int i = tid; i < c; i += 512)
            atomicAdd(&lcnt[buf[i] >> 17], 1);
    }
    __syncthreads();
    // scan lcnt[512] -> lbase (exclusive)
    {
        int a0 = 0, a1 = 0, s = 0;
        if (tid < 256) {
            a0 = lcnt[2 * tid]; a1 = lcnt[2 * tid + 1];
            s = a0 + a1;
            sc[tid] = s;
        }
        __syncthreads();
        for (int off = 1; off < 256; off <<= 1) {
            int t = (tid < 256 && tid >= off) ? sc[tid - off] : 0;
            __syncthreads();
            if (tid < 256) sc[tid] += t;
            __syncthreads();
        }
        if (tid < 256) {
            int excl = sc[tid] - s;
            lbase[2 * tid]     = excl;
            lbase[2 * tid + 1] = excl + a0;
        }
    }
    __syncthreads();
    int gb = bb[p];
    for (int i = tid; i < nn; i += 512)            // inclusive prefix -> cur
        cur[lo + i] = gb + lbase[i] + lcnt[i];
    __syncthreads();
    #pragma unroll
    for (int r = 0; r < NREP; ++r) {               // place into LDS staging
        int c = crp[r];
        const unsigned* buf = bbuf + r * RCAP;
        for (int i = tid; i < c; i += 512) {
            unsigned v = buf[i];
            int slot = atomicAdd(&lbase[v >> 17], 1);
            lcol[slot] = (int)(v & 0x1FFFFu);
        }
    }
    __syncthreads();
    for (int t = tid; t < cnttot; t += 512)        // dense stream-out
        col[gb + t] = lcol[t];
}

// ------------------------------- aggregation -------------------------------
// One wave per node, 16 streams: stream s = lane>>2 (0-7 pos stride-8,
// 8-15 neg), lane f = lane&3; each lane accumulates h8 chunks f and f+4.
// Reduce across strides with shfl_xor 4/8/16 (list bit 32 untouched).
// At the random-gather fabric ceiling (R11 probe) — do not touch.

__global__ void __launch_bounds__(256) agg_k(
    const h8* __restrict__ feat8,
    const int* __restrict__ cur, const int* __restrict__ col,
    h8* __restrict__ ag8, int n)
{
    int tid = threadIdx.x;
    int wave = tid >> 6, lane = tid & 63;
    int s = lane >> 2, f = lane & 3;
    int list = s >> 3;            // 0 = pos, 1 = neg
    int sub = s & 7;              // stride-8 phase

    int stride = gridDim.x * 4;
    for (int node = blockIdx.x * 4 + wave; node < n; node += stride) {
        int idx = list ? n + node : node;
        int r0 = idx ? cur[idx - 1] : 0;
        int r1 = cur[idx];

        h8 acc0 = {}, acc1 = {};
        #pragma unroll 2
        for (int it = r0 + sub; it < r1; it += 8) {
            unsigned srcb = (unsigned)col[it] * 8;
            acc0 = acc0 + feat8[srcb + f];
            acc1 = acc1 + feat8[srcb + 4 + f];
        }
        acc0 = acc0 + shflx8(acc0, 4);
        acc1 = acc1 + shflx8(acc1, 4);
        acc0 = acc0 + shflx8(acc0, 8);
        acc1 = acc1 + shflx8(acc1, 8);
        acc0 = acc0 + shflx8(acc0, 16);
        acc1 = acc1 + shflx8(acc1, 16);
        _Float16 inv = (_Float16)(1.0f / (float)max(r1 - r0, 1));
        h8 iv = { inv, inv, inv, inv, inv, inv, inv, inv };
        if (sub == 0) {
            ag8[(unsigned)(node * 16 + list * 8 + f)]     = acc0 * iv;
            ag8[(unsigned)(node * 16 + list * 8 + 4 + f)] = acc1 * iv;
        }
    }
}

// --------------------------------- GEMM ------------------------------------
// [64 nodes x 192] @ [192 x 64] per block (4 waves x 16-node tiles).
// A staged in LDS (row stride 200 fp16). D layout (verified):
// col = lane&15, row = (lane>>4)*4 + reg.

#define ROWP 200

__global__ void __launch_bounds__(256) gemm_k(
    const h8* __restrict__ ag8, const h8* __restrict__ feat8,
    const h8* __restrict__ Bp,
    const float* __restrict__ bp, const float* __restrict__ bn,
    float* __restrict__ outf, _Float16* __restrict__ outh,
    int f32out, int n)
{
    __shared__ _Float16 A_lds[64 * ROWP];   // 25.6 KB
    int tid = threadIdx.x;
    int base = blockIdx.x * 64;

    // stage A: per row, 16 h8 chunks of ag (128 h) + 8 h8 chunks of feat (64 h)
    for (int ch = tid; ch < 64 * 24; ch += 256) {
        int r = ch / 24, p = ch % 24;
        int row = min(base + r, n - 1);
        h8 v = (p < 16) ? ag8[(size_t)row * 16 + p]
                        : feat8[(size_t)row * 8 + (p - 16)];
        *(h8*)&A_lds[r * ROWP + p * 8] = v;
    }
    __syncthreads();

    int w = tid >> 6, lane = tid & 63;
    int m = lane & 15, g = lane >> 4;

    h8 a[6];
    #pragma unroll
    for (int kk = 0; kk < 6; ++kk)
        a[kk] = *(const h8*)&A_lds[(w * 16 + m) * ROWP + kk * 32 + g * 8];

    #pragma unroll
    for (int nt = 0; nt < 4; ++nt) {
        f32x4 acc = { 0.f, 0.f, 0.f, 0.f };
        #pragma unroll
        for (int kk = 0; kk < 6; ++kk) {
            h8 b = Bp[(kk * 4 + nt) * 64 + lane];
            acc = __builtin_amdgcn_mfma_f32_16x16x32_f16(a[kk], b, acc, 0, 0, 0);
        }
        int colc = nt * 16 + m;
        float bias = (colc < 32) ? bp[colc] : bn[colc - 32];
        #pragma unroll
        for (int reg = 0; reg < 4; ++reg) {
            int node = base + w * 16 + g * 4 + reg;
            if (node < n) {
                float val = fast_tanh(acc[reg] + bias);
                if (f32out) outf[(size_t)node * 64 + colc] = val;
                else        outh[(size_t)node * 64 + colc] = (_Float16)val;
            }
        }
    }
}

extern "C" void kernel_launch(void* const* d_in, const int* in_sizes, int n_in,
                              void* d_out, int out_size, void* d_ws, size_t ws_size,
                              hipStream_t stream)
{
    const float* x   = (const float*)d_in[0];
    const float* W1p = (const float*)d_in[1];
    const float* b1p = (const float*)d_in[2];
    const float* W1n = (const float*)d_in[3];
    const float* b1n = (const float*)d_in[4];
    const float* W2p = (const float*)d_in[5];
    const float* b2p = (const float*)d_in[6];
    const float* W2n = (const float*)d_in[7];
    const float* b2n = (const float*)d_in[8];
    const int*   pos = (const int*)d_in[9];
    const int*   neg = (const int*)d_in[10];

    int n = in_sizes[0] / 64;       // 100000
    int E = in_sizes[9] / 2;        // 1250000
    int n2 = 2 * n;
    int nb = (n2 + BSIZE - 1) / BSIZE;   // 391 buckets

    // ws: pcntR[8*512] | cur[2n] | col[2E] | Bpack[2*24*64*8 h] | xh[n*64 h] |
    //     U = max(ebuf nb*CAP u32, zh n*64 h)
    // ag (n x 128 h = 25.6MB) lives in d_out (each gemm block reads exactly
    // the ag rows it later overwrites).
    int*      pcntR = (int*)d_ws;
    int*      cur   = pcntR + NREP * NBMAX;
    int*      col   = cur + n2;
    _Float16* Bpack = (_Float16*)(col + 2 * (size_t)E);
    _Float16* xh    = Bpack + 2 * 24 * 64 * 8;
    unsigned* ebuf  = (unsigned*)(xh + (size_t)n * 64);
    _Float16* zh    = (_Float16*)ebuf;            // aliases ebuf (dead after scatter)
    h8*       ag8   = (h8*)d_out;

    hipMemsetAsync(pcntR, 0, NREP * NBMAX * sizeof(int), stream);

    int bblocks = 2048;             // 8 blocks/CU for the bucket phase
    int n4 = n * 16;
    int cvtBlocks = 512;            // grid-stride cvt

    mega_k<<<bblocks + cvtBlocks + 12, 256, 0, stream>>>(
        pos, neg, pcntR, ebuf, E, n, nb, bblocks,
        (const float4*)x, (h4*)xh, n4, cvtBlocks,
        W1p, W1n, W2p, W2n, Bpack);

    scatter_k<<<nb, 512, 0, stream>>>(ebuf, pcntR, cur, col, n, nb);

    int ablocks = 2048;
    int gblocks = (n + 63) / 64;

    // layer 1: agg(x) -> ag ; gemm(A1=[ag|x]) -> zh (fp16)
    agg_k <<<ablocks, 256, 0, stream>>>((const h8*)xh, cur, col, ag8, n);
    gemm_k<<<gblocks, 256, 0, stream>>>(ag8, (const h8*)xh, (const h8*)Bpack,
                                        b1p, b1n, nullptr, zh, 0, n);

    // layer 2: agg(z) -> ag ; gemm(A2=[Mp|Mn|z]) -> out (fp32)
    agg_k <<<ablocks, 256, 0, stream>>>((const h8*)zh, cur, col, ag8, n);
    gemm_k<<<gblocks, 256, 0, stream>>>(ag8, (const h8*)zh,
                                        (const h8*)(Bpack + 24 * 64 * 8),
                                        b2p, b2n, (float*)d_out, nullptr, 1, n);
}

// Round 11
// 264.378 us; speedup vs baseline: 1.0510x; 1.0020x over previous
//
#include <hip/hip_runtime.h>
#include <math.h>

// ---------------------------------------------------------------------------
// SGCN forward — CSR pull aggregation + MFMA dense layers.
//
// R15: R14 confirmed the reserve-contention theory (mega 52 -> sub-45, total
// 264.9). Remaining hidden time: scatter_k runs 391 blocks = 1.5/CU — its
// runtime is per-block SERIAL pass time (3 passes x 6400 records @ 512
// threads + two scans). Changes:
//   * scatter_k: 512 -> 1024 threads (halves every per-block pass; scan
//     sections stay 256-lane; LDS 39KB -> 2 blocks/CU at 1024 thr).
//   * mega_k bucket: stage the block's ~1221 packed records (+bucket ids) in
//     LDS during pass 1; pass 2 places from LDS (no global re-read).
// Frozen: agg_k (R11 null probe => random-gather fabric ceiling ~3.4TB/s),
// gemm_k, replica scheme (rep=bid&7 == XCD id under round-robin dispatch).
// ---------------------------------------------------------------------------

typedef _Float16 h4 __attribute__((ext_vector_type(4)));
typedef _Float16 h8 __attribute__((ext_vector_type(8)));
typedef float f32x4 __attribute__((ext_vector_type(4)));

__device__ inline h8 shflx8(h8 v, int m) {
    int4 i = __builtin_bit_cast(int4, v);
    i.x = __shfl_xor(i.x, m);
    i.y = __shfl_xor(i.y, m);
    i.z = __shfl_xor(i.z, m);
    i.w = __shfl_xor(i.w, m);
    return __builtin_bit_cast(h8, i);
}

__device__ inline float fast_tanh(float v) {
    float e = __expf(2.0f * v);
    return 1.0f - 2.0f / (e + 1.0f);
}

// ------------------------------- CSR build ---------------------------------
// Bucket = 512 consecutive flattened dst ids (2n space: pos then neg).
// Record = (nd & 511) << 17 | src   (src < 2^17, rel < 2^9 -> 26 bits).
// ebuf bucket region: 8 replica sub-chunks of RCAP records each.

#define BSHIFT 9
#define BSIZE  512
#define NBMAX  512
#define NREP   8
#define RCAP   1024   // per-(replica,bucket) capacity; mean 400, +31 sigma
#define CAP    (NREP * RCAP)
#define MAXPER 1280   // max edges per bucket block (2.5M / 2048 = 1221)

// ---- weight fragment maps (B 192x64 packed in MFMA fragment order) --------
// frag (kk,nt), lane l, elem j holds B[kk*32 + (l>>4)*8 + j][nt*16 + (l&15)].
// A1 row = [aggP(x) 0..63 | aggN(x) 64..127 | x 128..191]
// A2 row = [Mp(zp) 0..31 | Mp(zn) 32..63 | Mn(zp) 64..95 | Mn(zn) 96..127 |
//           zp 128..159 | zn 160..191]

__device__ inline float b1map(const float* W1p, const float* W1n, int k, int c)
{
    if (c < 32) {
        if (k < 64)   return W1p[k * 32 + c];            // aggP -> W1p rows 0..63
        if (k >= 128) return W1p[(k - 64) * 32 + c];     // x    -> W1p rows 64..127
        return 0.0f;
    } else {
        int cn = c - 32;
        if (k >= 64)  return W1n[(k - 64) * 32 + cn];    // aggN rows 0..63, x rows 64..127
        return 0.0f;
    }
}

__device__ inline float b2map(const float* W2p, const float* W2n, int k, int c)
{
    if (c < 32) {
        if (k < 32)               return W2p[k * 32 + c];              // Mp(zp)
        if (k >= 96 && k < 128)   return W2p[(k - 96 + 32) * 32 + c];  // Mn(zn)
        if (k >= 128 && k < 160)  return W2p[(k - 128 + 64) * 32 + c]; // zp
        return 0.0f;
    } else {
        int cn = c - 32;
        if (k >= 32 && k < 64)    return W2n[(k - 32) * 32 + cn];       // Mp(zn)
        if (k >= 64 && k < 96)    return W2n[(k - 64 + 32) * 32 + cn];  // Mn(zp)
        if (k >= 160)             return W2n[(k - 160 + 64) * 32 + cn]; // zn
        return 0.0f;
    }
}

// ---- merged: bucket (blocks [0,bblocks)) | cvt (grid-stride) | prep -------

__global__ void __launch_bounds__(256) mega_k(
    const int* __restrict__ pos, const int* __restrict__ neg,
    int* __restrict__ pcntR, unsigned* __restrict__ ebuf,
    int E, int n, int nb, int bblocks,
    const float4* __restrict__ x, h4* __restrict__ xh, int n4, int cvtBlocks,
    const float* __restrict__ W1p, const float* __restrict__ W1n,
    const float* __restrict__ W2p, const float* __restrict__ W2n,
    _Float16* __restrict__ Bpack)
{
    int tid = threadIdx.x;
    int bid = blockIdx.x;

    if (bid >= bblocks) {
        int cb = bid - bblocks;
        if (cb < cvtBlocks) {                       // ---- x -> fp16 (stride) ----
            int gs = cvtBlocks * 256;
            for (int i = cb * 256 + tid; i < n4; i += gs) {
                float4 v = x[i];
                h4 o = { (_Float16)v.x, (_Float16)v.y, (_Float16)v.z, (_Float16)v.w };
                xh[i] = o;
            }
        } else {                                    // ---- weight prep ----
            int slot = (cb - cvtBlocks) * 256 + tid;   // 0..3071
            if (slot < 2 * 24 * 64) {
                int mat  = slot / (24 * 64);
                int rem  = slot % (24 * 64);
                int fg   = rem / 64;          // kk*4 + nt
                int lane = rem % 64;
                int kk = fg >> 2, nt = fg & 3;
                int g = lane >> 4, m = lane & 15;
                _Float16* dst = Bpack + (size_t)slot * 8;
                int c = nt * 16 + m;
                #pragma unroll
                for (int j = 0; j < 8; ++j) {
                    int k = kk * 32 + g * 8 + j;
                    float v = mat ? b2map(W2p, W2n, k, c) : b1map(W1p, W1n, k, c);
                    dst[j] = (_Float16)v;
                }
            }
        }
        return;
    }

    // ---- bucket: single global read; records staged in LDS ----
    __shared__ int cnt[NBMAX], gbase[NBMAX];
    __shared__ unsigned erec[MAXPER];
    __shared__ unsigned short ep[MAXPER];
    int rep = bid & (NREP - 1);
    int per = (2 * E + bblocks - 1) / bblocks;
    int e0 = bid * per;
    int e1 = min(e0 + per, 2 * E);
    int cntloc = e1 - e0;

    for (int i = tid; i < nb; i += 256) cnt[i] = 0;
    __syncthreads();

    // pass 1: read edges once, stage record + bucket id, count
    for (int e = e0 + tid; e < e1; e += 256) {
        int nd, sr;
        if (e < E) { nd = pos[E + e];                 sr = pos[e]; }
        else       { int ee = e - E; nd = n + neg[E + ee]; sr = neg[ee]; }
        int p = nd >> BSHIFT;
        int li = e - e0;
        erec[li] = ((unsigned)(nd & (BSIZE - 1)) << 17) | (unsigned)sr;
        ep[li] = (unsigned short)p;
        atomicAdd(&cnt[p], 1);
    }
    __syncthreads();
    // reserve within own replica, reset cnt for rank use
    for (int i = tid; i < nb; i += 256) {
        int c = cnt[i];
        gbase[i] = c ? atomicAdd(&pcntR[rep * NBMAX + i], c) : 0;
        cnt[i] = 0;
    }
    __syncthreads();
    // pass 2: place from LDS
    for (int li = tid; li < cntloc; li += 256) {
        int p = ep[li];
        int r = gbase[p] + atomicAdd(&cnt[p], 1);
        if (r < RCAP)
            ebuf[(size_t)p * CAP + rep * RCAP + r] = erec[li];
    }
}

// One block per bucket, 1024 threads (scan sections use 256 lanes). Inline
// scan of per-bucket totals (sum over 8 replicas), LDS histogram over the 8
// sub-chunks -> scan -> dense cur write -> LDS staging -> contiguous out.
__global__ void __launch_bounds__(1024) scatter_k(
    const unsigned* __restrict__ ebuf, const int* __restrict__ pcntR,
    int* __restrict__ cur, int* __restrict__ col, int n, int nb)
{
    __shared__ int lcnt[BSIZE], lbase[BSIZE], sc[256], bb[NBMAX], crp[NREP];
    __shared__ int lcol[CAP];
    int p = blockIdx.x;
    int tid = threadIdx.x;
    int n2 = 2 * n;
    int lo = p << BSHIFT;
    int nn = min(BSIZE, n2 - lo);
    const unsigned* bbuf = ebuf + (size_t)p * CAP;

    if (tid < NREP) crp[tid] = min(pcntR[tid * NBMAX + p], RCAP);

    // inline exclusive scan of per-bucket totals — 256 scan lanes, 2 each
    {
        int a0 = 0, a1 = 0, s = 0;
        if (tid < 256) {
            #pragma unroll
            for (int r = 0; r < NREP; ++r) {
                if (2 * tid     < nb) a0 += min(pcntR[r * NBMAX + 2 * tid],     RCAP);
                if (2 * tid + 1 < nb) a1 += min(pcntR[r * NBMAX + 2 * tid + 1], RCAP);
            }
            s = a0 + a1;
            sc[tid] = s;
        }
        __syncthreads();
        for (int off = 1; off < 256; off <<= 1) {
            int t = (tid < 256 && tid >= off) ? sc[tid - off] : 0;
            __syncthreads();
            if (tid < 256) sc[tid] += t;
            __syncthreads();
        }
        if (tid < 256) {
            int excl = sc[tid] - s;
            bb[2 * tid]     = excl;
            bb[2 * tid + 1] = excl + a0;
        }
    }

    for (int i = tid; i < BSIZE; i += 1024) lcnt[i] = 0;
    __syncthreads();
    int cnttot = crp[0] + crp[1] + crp[2] + crp[3] +
                 crp[4] + crp[5] + crp[6] + crp[7];
    #pragma unroll
    for (int r = 0; r < NREP; ++r) {
        int c = crp[r];
        const unsigned* buf = bbuf + r * RCAP;
        for (int i = tid; i < c; i += 1024)
            atomicAdd(&lcnt[buf[i] >> 17], 1);
    }
    __syncthreads();
    // scan lcnt[512] -> lbase (exclusive)
    {
        int a0 = 0, a1 = 0, s = 0;
        if (tid < 256) {
            a0 = lcnt[2 * tid]; a1 = lcnt[2 * tid + 1];
            s = a0 + a1;
            sc[tid] = s;
        }
        __syncthreads();
        for (int off = 1; off < 256; off <<= 1) {
            int t = (tid < 256 && tid >= off) ? sc[tid - off] : 0;
            __syncthreads();
            if (tid < 256) sc[tid] += t;
            __syncthreads();
        }
        if (tid < 256) {
            int excl = sc[tid] - s;
            lbase[2 * tid]     = excl;
            lbase[2 * tid + 1] = excl + a0;
        }
    }
    __syncthreads();
    int gb = bb[p];
    for (int i = tid; i < nn; i += 1024)           // inclusive prefix -> cur
        cur[lo + i] = gb + lbase[i] + lcnt[i];
    __syncthreads();
    #pragma unroll
    for (int r = 0; r < NREP; ++r) {               // place into LDS staging
        int c = crp[r];
        const unsigned* buf = bbuf + r * RCAP;
        for (int i = tid; i < c; i += 1024) {
            unsigned v = buf[i];
            int slot = atomicAdd(&lbase[v >> 17], 1);
            lcol[slot] = (int)(v & 0x1FFFFu);
        }
    }
    __syncthreads();
    for (int t = tid; t < cnttot; t += 1024)       // dense stream-out
        col[gb + t] = lcol[t];
}

// ------------------------------- aggregation -------------------------------
// One wave per node, 16 streams: stream s = lane>>2 (0-7 pos stride-8,
// 8-15 neg), lane f = lane&3; each lane accumulates h8 chunks f and f+4.
// Reduce across strides with shfl_xor 4/8/16 (list bit 32 untouched).
// At the random-gather fabric ceiling (R11 probe) — do not touch.

__global__ void __launch_bounds__(256) agg_k(
    const h8* __restrict__ feat8,
    const int* __restrict__ cur, const int* __restrict__ col,
    h8* __restrict__ ag8, int n)
{
    int tid = threadIdx.x;
    int wave = tid >> 6, lane = tid & 63;
    int s = lane >> 2, f = lane & 3;
    int list = s >> 3;            // 0 = pos, 1 = neg
    int sub = s & 7;              // stride-8 phase

    int stride = gridDim.x * 4;
    for (int node = blockIdx.x * 4 + wave; node < n; node += stride) {
        int idx = list ? n + node : node;
        int r0 = idx ? cur[idx - 1] : 0;
        int r1 = cur[idx];

        h8 acc0 = {}, acc1 = {};
        #pragma unroll 2
        for (int it = r0 + sub; it < r1; it += 8) {
            unsigned srcb = (unsigned)col[it] * 8;
            acc0 = acc0 + feat8[srcb + f];
            acc1 = acc1 + feat8[srcb + 4 + f];
        }
        acc0 = acc0 + shflx8(acc0, 4);
        acc1 = acc1 + shflx8(acc1, 4);
        acc0 = acc0 + shflx8(acc0, 8);
        acc1 = acc1 + shflx8(acc1, 8);
        acc0 = acc0 + shflx8(acc0, 16);
        acc1 = acc1 + shflx8(acc1, 16);
        _Float16 inv = (_Float16)(1.0f / (float)max(r1 - r0, 1));
        h8 iv = { inv, inv, inv, inv, inv, inv, inv, inv };
        if (sub == 0) {
            ag8[(unsigned)(node * 16 + list * 8 + f)]     = acc0 * iv;
            ag8[(unsigned)(node * 16 + list * 8 + 4 + f)] = acc1 * iv;
        }
    }
}

// --------------------------------- GEMM ------------------------------------
// [64 nodes x 192] @ [192 x 64] per block (4 waves x 16-node tiles).
// A staged in LDS (row stride 200 fp16). D layout (verified):
// col = lane&15, row = (lane>>4)*4 + reg.

#define ROWP 200

__global__ void __launch_bounds__(256) gemm_k(
    const h8* __restrict__ ag8, const h8* __restrict__ feat8,
    const h8* __restrict__ Bp,
    const float* __restrict__ bp, const float* __restrict__ bn,
    float* __restrict__ outf, _Float16* __restrict__ outh,
    int f32out, int n)
{
    __shared__ _Float16 A_lds[64 * ROWP];   // 25.6 KB
    int tid = threadIdx.x;
    int base = blockIdx.x * 64;

    // stage A: per row, 16 h8 chunks of ag (128 h) + 8 h8 chunks of feat (64 h)
    for (int ch = tid; ch < 64 * 24; ch += 256) {
        int r = ch / 24, p = ch % 24;
        int row = min(base + r, n - 1);
        h8 v = (p < 16) ? ag8[(size_t)row * 16 + p]
                        : feat8[(size_t)row * 8 + (p - 16)];
        *(h8*)&A_lds[r * ROWP + p * 8] = v;
    }
    __syncthreads();

    int w = tid >> 6, lane = tid & 63;
    int m = lane & 15, g = lane >> 4;

    h8 a[6];
    #pragma unroll
    for (int kk = 0; kk < 6; ++kk)
        a[kk] = *(const h8*)&A_lds[(w * 16 + m) * ROWP + kk * 32 + g * 8];

    #pragma unroll
    for (int nt = 0; nt < 4; ++nt) {
        f32x4 acc = { 0.f, 0.f, 0.f, 0.f };
        #pragma unroll
        for (int kk = 0; kk < 6; ++kk) {
            h8 b = Bp[(kk * 4 + nt) * 64 + lane];
            acc = __builtin_amdgcn_mfma_f32_16x16x32_f16(a[kk], b, acc, 0, 0, 0);
        }
        int colc = nt * 16 + m;
        float bias = (colc < 32) ? bp[colc] : bn[colc - 32];
        #pragma unroll
        for (int reg = 0; reg < 4; ++reg) {
            int node = base + w * 16 + g * 4 + reg;
            if (node < n) {
                float val = fast_tanh(acc[reg] + bias);
                if (f32out) outf[(size_t)node * 64 + colc] = val;
                else        outh[(size_t)node * 64 + colc] = (_Float16)val;
            }
        }
    }
}

extern "C" void kernel_launch(void* const* d_in, const int* in_sizes, int n_in,
                              void* d_out, int out_size, void* d_ws, size_t ws_size,
                              hipStream_t stream)
{
    const float* x   = (const float*)d_in[0];
    const float* W1p = (const float*)d_in[1];
    const float* b1p = (const float*)d_in[2];
    const float* W1n = (const float*)d_in[3];
    const float* b1n = (const float*)d_in[4];
    const float* W2p = (const float*)d_in[5];
    const float* b2p = (const float*)d_in[6];
    const float* W2n = (const float*)d_in[7];
    const float* b2n = (const float*)d_in[8];
    const int*   pos = (const int*)d_in[9];
    const int*   neg = (const int*)d_in[10];

    int n = in_sizes[0] / 64;       // 100000
    int E = in_sizes[9] / 2;        // 1250000
    int n2 = 2 * n;
    int nb = (n2 + BSIZE - 1) / BSIZE;   // 391 buckets

    // ws: pcntR[8*512] | cur[2n] | col[2E] | Bpack[2*24*64*8 h] | xh[n*64 h] |
    //     U = max(ebuf nb*CAP u32, zh n*64 h)
    // ag (n x 128 h = 25.6MB) lives in d_out (each gemm block reads exactly
    // the ag rows it later overwrites).
    int*      pcntR = (int*)d_ws;
    int*      cur   = pcntR + NREP * NBMAX;
    int*      col   = cur + n2;
    _Float16* Bpack = (_Float16*)(col + 2 * (size_t)E);
    _Float16* xh    = Bpack + 2 * 24 * 64 * 8;
    unsigned* ebuf  = (unsigned*)(xh + (size_t)n * 64);
    _Float16* zh    = (_Float16*)ebuf;            // aliases ebuf (dead after scatter)
    h8*       ag8   = (h8*)d_out;

    hipMemsetAsync(pcntR, 0, NREP * NBMAX * sizeof(int), stream);

    int bblocks = 2048;             // 8 blocks/CU for the bucket phase
    int n4 = n * 16;
    int cvtBlocks = 512;            // grid-stride cvt

    mega_k<<<bblocks + cvtBlocks + 12, 256, 0, stream>>>(
        pos, neg, pcntR, ebuf, E, n, nb, bblocks,
        (const float4*)x, (h4*)xh, n4, cvtBlocks,
        W1p, W1n, W2p, W2n, Bpack);

    scatter_k<<<nb, 1024, 0, stream>>>(ebuf, pcntR, cur, col, n, nb);

    int ablocks = 2048;
    int gblocks = (n + 63) / 64;

    // layer 1: agg(x) -> ag ; gemm(A1=[ag|x]) -> zh (fp16)
    agg_k <<<ablocks, 256, 0, stream>>>((const h8*)xh, cur, col, ag8, n);
    gemm_k<<<gblocks, 256, 0, stream>>>(ag8, (const h8*)xh, (const h8*)Bpack,
                                        b1p, b1n, nullptr, zh, 0, n);

    // layer 2: agg(z) -> ag ; gemm(A2=[Mp|Mn|z]) -> out (fp32)
    agg_k <<<ablocks, 256, 0, stream>>>((const h8*)zh, cur, col, ag8, n);
    gemm_k<<<gblocks, 256, 0, stream>>>(ag8, (const h8*)zh,
                                        (const h8*)(Bpack + 24 * 64 * 8),
                                        b2p, b2n, (float*)d_out, nullptr, 1, n);
}

// Round 12
// 262.590 us; speedup vs baseline: 1.0582x; 1.0068x over previous
//
#include <hip/hip_runtime.h>
#include <math.h>

// ---------------------------------------------------------------------------
// SGCN forward — CSR pull aggregation + MFMA dense layers.
//
// R16: R15 was null (predicted -12, got -0.5) -> hidden-time model wrong.
// Known facts: mega pass-2 writes 57MB for 10MB of records (random 4B
// stores, ~5.7x amp — R13 counter); gemm's ag round-trip (25.6MB via d_out)
// is read cross-XCD. Fixes:
//   * mega: 512 bucket blocks; LDS counting-sort records by bucket, write in
//     sorted order -> ~12-word coalesced runs per chunk (amp -> ~1.6x).
//   * gemm: XCD-affine node map. agg block i (XCD i%8) wrote nodes 4i..4i+3;
//     gemm block g takes nodes 32*(16*(g>>3)+(r>>2))+4*(g&7)+(r&3) — the rows
//     its own XCD L2 holds (ag 25.6MB vs 32MB aggregate L2, L2 not flushed
//     between kernels). Bijective map; perf-only assumption.
// Frozen: agg_k (R11 null probe => random-gather fabric ceiling), scatter_k,
// replica reserve scheme (R14 win), cvt/prep.
// ---------------------------------------------------------------------------

typedef _Float16 h4 __attribute__((ext_vector_type(4)));
typedef _Float16 h8 __attribute__((ext_vector_type(8)));
typedef float f32x4 __attribute__((ext_vector_type(4)));

__device__ inline h8 shflx8(h8 v, int m) {
    int4 i = __builtin_bit_cast(int4, v);
    i.x = __shfl_xor(i.x, m);
    i.y = __shfl_xor(i.y, m);
    i.z = __shfl_xor(i.z, m);
    i.w = __shfl_xor(i.w, m);
    return __builtin_bit_cast(h8, i);
}

__device__ inline float fast_tanh(float v) {
    float e = __expf(2.0f * v);
    return 1.0f - 2.0f / (e + 1.0f);
}

// ------------------------------- CSR build ---------------------------------
// Bucket = 512 consecutive flattened dst ids (2n space: pos then neg).
// Record = (nd & 511) << 17 | src   (src < 2^17, rel < 2^9 -> 26 bits).
// ebuf bucket region: 8 replica sub-chunks of RCAP records each.

#define BSHIFT 9
#define BSIZE  512
#define NBMAX  512
#define NREP   8
#define RCAP   1024   // per-(replica,bucket) capacity; mean 800, +8 sigma
#define CAP    (NREP * RCAP)
#define MAXPER 4992   // max edges per bucket block (2.5M / 512 = 4884)

// ---- weight fragment maps (B 192x64 packed in MFMA fragment order) --------
// frag (kk,nt), lane l, elem j holds B[kk*32 + (l>>4)*8 + j][nt*16 + (l&15)].
// A1 row = [aggP(x) 0..63 | aggN(x) 64..127 | x 128..191]
// A2 row = [Mp(zp) 0..31 | Mp(zn) 32..63 | Mn(zp) 64..95 | Mn(zn) 96..127 |
//           zp 128..159 | zn 160..191]

__device__ inline float b1map(const float* W1p, const float* W1n, int k, int c)
{
    if (c < 32) {
        if (k < 64)   return W1p[k * 32 + c];            // aggP -> W1p rows 0..63
        if (k >= 128) return W1p[(k - 64) * 32 + c];     // x    -> W1p rows 64..127
        return 0.0f;
    } else {
        int cn = c - 32;
        if (k >= 64)  return W1n[(k - 64) * 32 + cn];    // aggN rows 0..63, x rows 64..127
        return 0.0f;
    }
}

__device__ inline float b2map(const float* W2p, const float* W2n, int k, int c)
{
    if (c < 32) {
        if (k < 32)               return W2p[k * 32 + c];              // Mp(zp)
        if (k >= 96 && k < 128)   return W2p[(k - 96 + 32) * 32 + c];  // Mn(zn)
        if (k >= 128 && k < 160)  return W2p[(k - 128 + 64) * 32 + c]; // zp
        return 0.0f;
    } else {
        int cn = c - 32;
        if (k >= 32 && k < 64)    return W2n[(k - 32) * 32 + cn];       // Mp(zn)
        if (k >= 64 && k < 96)    return W2n[(k - 64 + 32) * 32 + cn];  // Mn(zp)
        if (k >= 160)             return W2n[(k - 160 + 64) * 32 + cn]; // zn
        return 0.0f;
    }
}

// ---- merged: bucket (blocks [0,bblocks)) | cvt (grid-stride) | prep -------

__global__ void __launch_bounds__(256) mega_k(
    const int* __restrict__ pos, const int* __restrict__ neg,
    int* __restrict__ pcntR, unsigned* __restrict__ ebuf,
    int E, int n, int nb, int bblocks,
    const float4* __restrict__ x, h4* __restrict__ xh, int n4, int cvtBlocks,
    const float* __restrict__ W1p, const float* __restrict__ W1n,
    const float* __restrict__ W2p, const float* __restrict__ W2n,
    _Float16* __restrict__ Bpack)
{
    int tid = threadIdx.x;
    int bid = blockIdx.x;

    if (bid >= bblocks) {
        int cb = bid - bblocks;
        if (cb < cvtBlocks) {                       // ---- x -> fp16 (stride) ----
            int gs = cvtBlocks * 256;
            for (int i = cb * 256 + tid; i < n4; i += gs) {
                float4 v = x[i];
                h4 o = { (_Float16)v.x, (_Float16)v.y, (_Float16)v.z, (_Float16)v.w };
                xh[i] = o;
            }
        } else {                                    // ---- weight prep ----
            int slot = (cb - cvtBlocks) * 256 + tid;   // 0..3071
            if (slot < 2 * 24 * 64) {
                int mat  = slot / (24 * 64);
                int rem  = slot % (24 * 64);
                int fg   = rem / 64;          // kk*4 + nt
                int lane = rem % 64;
                int kk = fg >> 2, nt = fg & 3;
                int g = lane >> 4, m = lane & 15;
                _Float16* dst = Bpack + (size_t)slot * 8;
                int c = nt * 16 + m;
                #pragma unroll
                for (int j = 0; j < 8; ++j) {
                    int k = kk * 32 + g * 8 + j;
                    float v = mat ? b2map(W2p, W2n, k, c) : b1map(W1p, W1n, k, c);
                    dst[j] = (_Float16)v;
                }
            }
        }
        return;
    }

    // ---- bucket: read edges once; LDS counting-sort; coalesced writes ----
    __shared__ int cnt[NBMAX], gbase[NBMAX], lofs[NBMAX], sc2[256];
    __shared__ unsigned erec[MAXPER], sorted[MAXPER];
    __shared__ unsigned short ep[MAXPER], pd[MAXPER];
    int rep = bid & (NREP - 1);
    int per = (2 * E + bblocks - 1) / bblocks;
    int e0 = bid * per;
    int e1 = min(e0 + per, 2 * E);
    int cntloc = e1 - e0;

    for (int i = tid; i < nb; i += 256) cnt[i] = 0;
    __syncthreads();

    // pass 1: read edges once, stage record + bucket id, count
    for (int e = e0 + tid; e < e1; e += 256) {
        int nd, sr;
        if (e < E) { nd = pos[E + e];                 sr = pos[e]; }
        else       { int ee = e - E; nd = n + neg[E + ee]; sr = neg[ee]; }
        int p = nd >> BSHIFT;
        int li = e - e0;
        erec[li] = ((unsigned)(nd & (BSIZE - 1)) << 17) | (unsigned)sr;
        ep[li] = (unsigned short)p;
        atomicAdd(&cnt[p], 1);
    }
    __syncthreads();
    // reserve within own replica
    for (int i = tid; i < nb; i += 256) {
        int c = cnt[i];
        gbase[i] = c ? atomicAdd(&pcntR[rep * NBMAX + i], c) : 0;
    }
    // block-local exclusive scan of cnt -> lofs (256 lanes, 2 elems each)
    {
        int a0 = (2 * tid     < nb) ? cnt[2 * tid]     : 0;
        int a1 = (2 * tid + 1 < nb) ? cnt[2 * tid + 1] : 0;
        int s = a0 + a1;
        sc2[tid] = s;
        __syncthreads();
        for (int off = 1; off < 256; off <<= 1) {
            int t = (tid >= off) ? sc2[tid - off] : 0;
            __syncthreads();
            sc2[tid] += t;
            __syncthreads();
        }
        int excl = sc2[tid] - s;
        if (2 * tid     < nb) lofs[2 * tid]     = excl;
        if (2 * tid + 1 < nb) lofs[2 * tid + 1] = excl + a0;
    }
    __syncthreads();
    for (int i = tid; i < nb; i += 256) cnt[i] = 0;   // reuse as rank
    __syncthreads();
    // place into block-sorted order
    for (int li = tid; li < cntloc; li += 256) {
        int p = ep[li];
        int r = atomicAdd(&cnt[p], 1);
        int idx = lofs[p] + r;
        sorted[idx] = erec[li];
        pd[idx] = (unsigned short)p;
    }
    __syncthreads();
    // write out in sorted order: consecutive t within a bucket -> consecutive
    // global addresses (coalesced runs of ~12 words per chunk)
    for (int t = tid; t < cntloc; t += 256) {
        int p = pd[t];
        int g = gbase[p] + (t - lofs[p]);
        if (g < RCAP)
            ebuf[(size_t)p * CAP + rep * RCAP + g] = sorted[t];
    }
}

// One block per bucket, 1024 threads (scan sections use 256 lanes). Inline
// scan of per-bucket totals (sum over 8 replicas), LDS histogram over the 8
// sub-chunks -> scan -> dense cur write -> LDS staging -> contiguous out.
__global__ void __launch_bounds__(1024) scatter_k(
    const unsigned* __restrict__ ebuf, const int* __restrict__ pcntR,
    int* __restrict__ cur, int* __restrict__ col, int n, int nb)
{
    __shared__ int lcnt[BSIZE], lbase[BSIZE], sc[256], bb[NBMAX], crp[NREP];
    __shared__ int lcol[CAP];
    int p = blockIdx.x;
    int tid = threadIdx.x;
    int n2 = 2 * n;
    int lo = p << BSHIFT;
    int nn = min(BSIZE, n2 - lo);
    const unsigned* bbuf = ebuf + (size_t)p * CAP;

    if (tid < NREP) crp[tid] = min(pcntR[tid * NBMAX + p], RCAP);

    // inline exclusive scan of per-bucket totals — 256 scan lanes, 2 each
    {
        int a0 = 0, a1 = 0, s = 0;
        if (tid < 256) {
            #pragma unroll
            for (int r = 0; r < NREP; ++r) {
                if (2 * tid     < nb) a0 += min(pcntR[r * NBMAX + 2 * tid],     RCAP);
                if (2 * tid + 1 < nb) a1 += min(pcntR[r * NBMAX + 2 * tid + 1], RCAP);
            }
            s = a0 + a1;
            sc[tid] = s;
        }
        __syncthreads();
        for (int off = 1; off < 256; off <<= 1) {
            int t = (tid < 256 && tid >= off) ? sc[tid - off] : 0;
            __syncthreads();
            if (tid < 256) sc[tid] += t;
            __syncthreads();
        }
        if (tid < 256) {
            int excl = sc[tid] - s;
            bb[2 * tid]     = excl;
            bb[2 * tid + 1] = excl + a0;
        }
    }

    for (int i = tid; i < BSIZE; i += 1024) lcnt[i] = 0;
    __syncthreads();
    int cnttot = crp[0] + crp[1] + crp[2] + crp[3] +
                 crp[4] + crp[5] + crp[6] + crp[7];
    #pragma unroll
    for (int r = 0; r < NREP; ++r) {
        int c = crp[r];
        const unsigned* buf = bbuf + r * RCAP;
        for (int i = tid; i < c; i += 1024)
            atomicAdd(&lcnt[buf[i] >> 17], 1);
    }
    __syncthreads();
    // scan lcnt[512] -> lbase (exclusive)
    {
        int a0 = 0, a1 = 0, s = 0;
        if (tid < 256) {
            a0 = lcnt[2 * tid]; a1 = lcnt[2 * tid + 1];
            s = a0 + a1;
            sc[tid] = s;
        }
        __syncthreads();
        for (int off = 1; off < 256; off <<= 1) {
            int t = (tid < 256 && tid >= off) ? sc[tid - off] : 0;
            __syncthreads();
            if (tid < 256) sc[tid] += t;
            __syncthreads();
        }
        if (tid < 256) {
            int excl = sc[tid] - s;
            lbase[2 * tid]     = excl;
            lbase[2 * tid + 1] = excl + a0;
        }
    }
    __syncthreads();
    int gb = bb[p];
    for (int i = tid; i < nn; i += 1024)           // inclusive prefix -> cur
        cur[lo + i] = gb + lbase[i] + lcnt[i];
    __syncthreads();
    #pragma unroll
    for (int r = 0; r < NREP; ++r) {               // place into LDS staging
        int c = crp[r];
        const unsigned* buf = bbuf + r * RCAP;
        for (int i = tid; i < c; i += 1024) {
            unsigned v = buf[i];
            int slot = atomicAdd(&lbase[v >> 17], 1);
            lcol[slot] = (int)(v & 0x1FFFFu);
        }
    }
    __syncthreads();
    for (int t = tid; t < cnttot; t += 1024)       // dense stream-out
        col[gb + t] = lcol[t];
}

// ------------------------------- aggregation -------------------------------
// One wave per node, 16 streams: stream s = lane>>2 (0-7 pos stride-8,
// 8-15 neg), lane f = lane&3; each lane accumulates h8 chunks f and f+4.
// Reduce across strides with shfl_xor 4/8/16 (list bit 32 untouched).
// At the random-gather fabric ceiling (R11 probe) — do not touch.
// NOTE: block i (XCD i%8) writes nodes 4i..4i+3 (+8192 stride) -> node j's
// ag row lands in L2 of XCD (j/4)%8. gemm_k's node map exploits this.

__global__ void __launch_bounds__(256) agg_k(
    const h8* __restrict__ feat8,
    const int* __restrict__ cur, const int* __restrict__ col,
    h8* __restrict__ ag8, int n)
{
    int tid = threadIdx.x;
    int wave = tid >> 6, lane = tid & 63;
    int s = lane >> 2, f = lane & 3;
    int list = s >> 3;            // 0 = pos, 1 = neg
    int sub = s & 7;              // stride-8 phase

    int stride = gridDim.x * 4;
    for (int node = blockIdx.x * 4 + wave; node < n; node += stride) {
        int idx = list ? n + node : node;
        int r0 = idx ? cur[idx - 1] : 0;
        int r1 = cur[idx];

        h8 acc0 = {}, acc1 = {};
        #pragma unroll 2
        for (int it = r0 + sub; it < r1; it += 8) {
            unsigned srcb = (unsigned)col[it] * 8;
            acc0 = acc0 + feat8[srcb + f];
            acc1 = acc1 + feat8[srcb + 4 + f];
        }
        acc0 = acc0 + shflx8(acc0, 4);
        acc1 = acc1 + shflx8(acc1, 4);
        acc0 = acc0 + shflx8(acc0, 8);
        acc1 = acc1 + shflx8(acc1, 8);
        acc0 = acc0 + shflx8(acc0, 16);
        acc1 = acc1 + shflx8(acc1, 16);
        _Float16 inv = (_Float16)(1.0f / (float)max(r1 - r0, 1));
        h8 iv = { inv, inv, inv, inv, inv, inv, inv, inv };
        if (sub == 0) {
            ag8[(unsigned)(node * 16 + list * 8 + f)]     = acc0 * iv;
            ag8[(unsigned)(node * 16 + list * 8 + 4 + f)] = acc1 * iv;
        }
    }
}

// --------------------------------- GEMM ------------------------------------
// [64 nodes x 192] @ [192 x 64] per block (4 waves x 16-node tiles).
// XCD-affine node map: block g (XCD g%8) processes the nodes whose ag rows
// were written by agg blocks on the same XCD: node(r) =
// 32*(16*(g>>3) + (r>>2)) + 4*(g&7) + (r&3)  (bijective onto [0, 32*16*nkb)).
// A staged in LDS (row stride 200 fp16). D layout (verified):
// col = lane&15, row = (lane>>4)*4 + reg.

#define ROWP 200

__device__ inline int nmap(int g, int r) {
    return 32 * (16 * (g >> 3) + (r >> 2)) + 4 * (g & 7) + (r & 3);
}

__global__ void __launch_bounds__(256) gemm_k(
    const h8* __restrict__ ag8, const h8* __restrict__ feat8,
    const h8* __restrict__ Bp,
    const float* __restrict__ bp, const float* __restrict__ bn,
    float* __restrict__ outf, _Float16* __restrict__ outh,
    int f32out, int n)
{
    __shared__ _Float16 A_lds[64 * ROWP];   // 25.6 KB
    int tid = threadIdx.x;
    int bid = blockIdx.x;

    // stage A: per row, 16 h8 chunks of ag (128 h) + 8 h8 chunks of feat (64 h)
    for (int ch = tid; ch < 64 * 24; ch += 256) {
        int r = ch / 24, p = ch % 24;
        int row = min(nmap(bid, r), n - 1);
        h8 v = (p < 16) ? ag8[(size_t)row * 16 + p]
                        : feat8[(size_t)row * 8 + (p - 16)];
        *(h8*)&A_lds[r * ROWP + p * 8] = v;
    }
    __syncthreads();

    int w = tid >> 6, lane = tid & 63;
    int m = lane & 15, g = lane >> 4;

    h8 a[6];
    #pragma unroll
    for (int kk = 0; kk < 6; ++kk)
        a[kk] = *(const h8*)&A_lds[(w * 16 + m) * ROWP + kk * 32 + g * 8];

    #pragma unroll
    for (int nt = 0; nt < 4; ++nt) {
        f32x4 acc = { 0.f, 0.f, 0.f, 0.f };
        #pragma unroll
        for (int kk = 0; kk < 6; ++kk) {
            h8 b = Bp[(kk * 4 + nt) * 64 + lane];
            acc = __builtin_amdgcn_mfma_f32_16x16x32_f16(a[kk], b, acc, 0, 0, 0);
        }
        int colc = nt * 16 + m;
        float bias = (colc < 32) ? bp[colc] : bn[colc - 32];
        #pragma unroll
        for (int reg = 0; reg < 4; ++reg) {
            int node = nmap(bid, w * 16 + g * 4 + reg);
            if (node < n) {
                float val = fast_tanh(acc[reg] + bias);
                if (f32out) outf[(size_t)node * 64 + colc] = val;
                else        outh[(size_t)node * 64 + colc] = (_Float16)val;
            }
        }
    }
}

extern "C" void kernel_launch(void* const* d_in, const int* in_sizes, int n_in,
                              void* d_out, int out_size, void* d_ws, size_t ws_size,
                              hipStream_t stream)
{
    const float* x   = (const float*)d_in[0];
    const float* W1p = (const float*)d_in[1];
    const float* b1p = (const float*)d_in[2];
    const float* W1n = (const float*)d_in[3];
    const float* b1n = (const float*)d_in[4];
    const float* W2p = (const float*)d_in[5];
    const float* b2p = (const float*)d_in[6];
    const float* W2n = (const float*)d_in[7];
    const float* b2n = (const float*)d_in[8];
    const int*   pos = (const int*)d_in[9];
    const int*   neg = (const int*)d_in[10];

    int n = in_sizes[0] / 64;       // 100000
    int E = in_sizes[9] / 2;        // 1250000
    int n2 = 2 * n;
    int nb = (n2 + BSIZE - 1) / BSIZE;   // 391 buckets

    // ws: pcntR[8*512] | cur[2n] | col[2E] | Bpack[2*24*64*8 h] | xh[n*64 h] |
    //     U = max(ebuf nb*CAP u32, zh n*64 h)
    // ag (n x 128 h = 25.6MB) lives in d_out (each gemm block reads exactly
    // the ag rows it later overwrites).
    int*      pcntR = (int*)d_ws;
    int*      cur   = pcntR + NREP * NBMAX;
    int*      col   = cur + n2;
    _Float16* Bpack = (_Float16*)(col + 2 * (size_t)E);
    _Float16* xh    = Bpack + 2 * 24 * 64 * 8;
    unsigned* ebuf  = (unsigned*)(xh + (size_t)n * 64);
    _Float16* zh    = (_Float16*)ebuf;            // aliases ebuf (dead after scatter)
    h8*       ag8   = (h8*)d_out;

    hipMemsetAsync(pcntR, 0, NREP * NBMAX * sizeof(int), stream);

    int bblocks = 512;              // 2 blocks/CU; LDS-sorted coalesced scatter
    int n4 = n * 16;
    int cvtBlocks = 512;            // grid-stride cvt

    mega_k<<<bblocks + cvtBlocks + 12, 256, 0, stream>>>(
        pos, neg, pcntR, ebuf, E, n, nb, bblocks,
        (const float4*)x, (h4*)xh, n4, cvtBlocks,
        W1p, W1n, W2p, W2n, Bpack);

    scatter_k<<<nb, 1024, 0, stream>>>(ebuf, pcntR, cur, col, n, nb);

    int ablocks = 2048;
    int gblocks = (n + 63) / 64 + 5;   // 1568: covers the bijective node map

    // layer 1: agg(x) -> ag ; gemm(A1=[ag|x]) -> zh (fp16)
    agg_k <<<ablocks, 256, 0, stream>>>((const h8*)xh, cur, col, ag8, n);
    gemm_k<<<gblocks, 256, 0, stream>>>(ag8, (const h8*)xh, (const h8*)Bpack,
                                        b1p, b1n, nullptr, zh, 0, n);

    // layer 2: agg(z) -> ag ; gemm(A2=[Mp|Mn|z]) -> out (fp32)
    agg_k <<<ablocks, 256, 0, stream>>>((const h8*)zh, cur, col, ag8, n);
    gemm_k<<<gblocks, 256, 0, stream>>>(ag8, (const h8*)zh,
                                        (const h8*)(Bpack + 24 * 64 * 8),
                                        b2p, b2n, (float*)d_out, nullptr, 1, n);
}